// Round 1
// 239.244 us; speedup vs baseline: 1.0072x; 1.0072x over previous
//
#include <hip/hip_runtime.h>

// LeakyIntegrator: T=4096 scan over B=8192 columns, fp32. x is EXACTLY {0,1}.
// Algebraic reduction: with m_t = d*(m_{t-1}+x_t)   (= n10+n11, decayed ones),
//   na1_t = m_{t-1}                       (EXACT identity, same fp op sequence)
//   na0_t = S_t - m_{t-1},  S_t = d*(S_{t-1}+1) = d(1-d^t)/(1-d)   (data-independent)
//   n10_t = m_t - n11_t
// => only TWO data-dependent states (m, n11) + bit-packed x.
// Pass1: chunk-local (m,n11) scans from 0 + bit-pack; software-pipelined float4 loads.
// Scan : 2*B threads fold 64 chunk locals -> incoming states in place.
// Pass2: rescan from incoming state; na_sum from closed form; ONE rcp per element
//        (x selects num/den); float4 nontemporal stores.
// ws layout (8 MiB total):
//   [0, 2 MiB)  : m   locals [NCHUNK][B_DIM] float
//   [2, 4 MiB)  : n11 locals [NCHUNK][B_DIM] float
//   [4, 8 MiB)  : packed x bits [NCHUNK][B_DIM] u64

constexpr int T_DIM  = 4096;
constexpr int B_DIM  = 8192;
constexpr int NCHUNK = 64;
constexpr int CLEN   = T_DIM / NCHUNK;   // 64
constexpr int VEC    = 4;                // columns per thread (float4)
constexpr int UNROLL = 8;                // rows per load batch

typedef float v4f __attribute__((ext_vector_type(4)));
typedef unsigned long long u64;
typedef u64 v2u __attribute__((ext_vector_type(2)));

__global__ __launch_bounds__(256) void partial_kernel(
    const float* __restrict__ x, const float* __restrict__ dptr,
    float* __restrict__ ws)
{
    const float d  = *dptr;
    const int   c  = blockIdx.y;
    const int   b0 = (blockIdx.x * blockDim.x + threadIdx.x) * VEC;
    const long  t0 = (long)c * CLEN;

    float prev[VEC];
    if (c == 0) {
        #pragma unroll
        for (int j = 0; j < VEC; ++j) prev[j] = 0.0f;
    } else {
        const v4f pv = *reinterpret_cast<const v4f*>(x + (t0 - 1) * B_DIM + b0);
        #pragma unroll
        for (int j = 0; j < VEC; ++j) prev[j] = pv[j];
    }

    float m[VEC]   = {0.f, 0.f, 0.f, 0.f};
    float n11[VEC] = {0.f, 0.f, 0.f, 0.f};
    u64   mask[VEC] = {0ull, 0ull, 0ull, 0ull};

    const float* p = x + t0 * B_DIM + b0;

    // two-batch software pipeline: next batch's loads are in flight while the
    // current batch is consumed. Static indexing only (named A/Bv), full unroll.
    v4f A[UNROLL], Bv[UNROLL];
    #pragma unroll
    for (int u = 0; u < UNROLL; ++u)
        A[u] = *reinterpret_cast<const v4f*>(p + (size_t)u * B_DIM);

    auto compute = [&](const v4f* buf, int kbase) {
        #pragma unroll
        for (int u = 0; u < UNROLL; ++u) {
            const int k = kbase + u;
            #pragma unroll
            for (int j = 0; j < VEC; ++j) {
                const float xt = buf[u][j];
                mask[j] |= (u64)(unsigned)xt << k;     // xt is exactly 0.0 or 1.0
                m[j]   = d * (m[j] + xt);
                n11[j] = d * (n11[j] + xt * prev[j]);
                prev[j] = xt;
            }
        }
    };

    #pragma unroll
    for (int kk = 0; kk < CLEN; kk += 2 * UNROLL) {
        #pragma unroll
        for (int u = 0; u < UNROLL; ++u)
            Bv[u] = *reinterpret_cast<const v4f*>(p + (size_t)(kk + UNROLL + u) * B_DIM);
        compute(A, kk);
        if (kk + 2 * UNROLL < CLEN) {          // compile-time after unroll
            #pragma unroll
            for (int u = 0; u < UNROLL; ++u)
                A[u] = *reinterpret_cast<const v4f*>(p + (size_t)(kk + 2 * UNROLL + u) * B_DIM);
        }
        compute(Bv, kk + UNROLL);
    }

    float* wm = ws + (size_t)c * B_DIM + b0;
    v4f mv, nv;
    #pragma unroll
    for (int j = 0; j < VEC; ++j) { mv[j] = m[j]; nv[j] = n11[j]; }
    *reinterpret_cast<v4f*>(wm)                                = mv;
    *reinterpret_cast<v4f*>(wm + (size_t)NCHUNK * B_DIM)       = nv;

    u64* bits = reinterpret_cast<u64*>(ws + (size_t)2 * NCHUNK * B_DIM);
    v2u b01, b23;
    b01[0] = mask[0]; b01[1] = mask[1];
    b23[0] = mask[2]; b23[1] = mask[3];
    *reinterpret_cast<v2u*>(&bits[(size_t)c * B_DIM + b0])     = b01;
    *reinterpret_cast<v2u*>(&bits[(size_t)c * B_DIM + b0 + 2]) = b23;
}

// One thread per (state, column): 2*8192 = 16384 threads. All 64 chunk-local
// loads hoisted into registers before the serial fold.
__global__ __launch_bounds__(256) void scan_kernel(
    const float* __restrict__ dptr, float* __restrict__ ws)
{
    float dL = *dptr;                 // d^CLEN, CLEN = 64 = 2^6
    #pragma unroll
    for (int i = 0; i < 6; ++i) dL = dL * dL;

    const int tid = blockIdx.x * blockDim.x + threadIdx.x;     // [0, 2*B)
    float* p = ws + (size_t)(tid >> 13) * NCHUNK * B_DIM + (tid & (B_DIM - 1));

    float l[NCHUNK];
    #pragma unroll
    for (int c = 0; c < NCHUNK; ++c) l[c] = p[(size_t)c * B_DIM];

    float s = 0.f;
    #pragma unroll
    for (int c = 0; c < NCHUNK; ++c) {
        p[(size_t)c * B_DIM] = s;     // incoming state for chunk c
        s = dL * s + l[c];
    }
}

__global__ __launch_bounds__(256) void final_kernel(
    const float* __restrict__ dptr, const float* __restrict__ ws,
    float* __restrict__ out)
{
    const float d = *dptr;
    float dL = d;
    #pragma unroll
    for (int i = 0; i < 6; ++i) dL = dL * dL;                  // d^64

    const int c  = blockIdx.y;
    const int b0 = (blockIdx.x * blockDim.x + threadIdx.x) * VEC;

    const float* w = ws + (size_t)c * B_DIM + b0;
    const v4f mi = *reinterpret_cast<const v4f*>(w);
    const v4f ni = *reinterpret_cast<const v4f*>(w + (size_t)NCHUNK * B_DIM);
    float m[VEC], n11[VEC];
    #pragma unroll
    for (int j = 0; j < VEC; ++j) { m[j] = mi[j]; n11[j] = ni[j]; }

    // incoming na_sum = d*(1 - d^(64c)) / (1-d); 1-d is EXACT for d in [0.5,1)
    float dLc = 1.f, sq = dL;
    int cc = c;
    #pragma unroll
    for (int i = 0; i < 6; ++i) { if (cc & 1) dLc *= sq; sq *= sq; cc >>= 1; }
    float na = d * (1.f - dLc) / (1.f - d);

    const u64* bits = reinterpret_cast<const u64*>(ws + (size_t)2 * NCHUNK * B_DIM);
    u64 mask[VEC];
    #pragma unroll
    for (int j = 0; j < VEC; ++j) mask[j] = bits[(size_t)c * B_DIM + b0 + j];

    bool pb[VEC];
    if (c == 0) {
        #pragma unroll
        for (int j = 0; j < VEC; ++j) pb[j] = false;
    } else {
        #pragma unroll
        for (int j = 0; j < VEC; ++j)
            pb[j] = (bits[(size_t)(c - 1) * B_DIM + b0 + j] >> 63) & 1ull;
    }

    float* q = out + (size_t)c * CLEN * B_DIM + b0;
    for (int kk = 0; kk < CLEN; kk += UNROLL) {
        #pragma unroll
        for (int u = 0; u < UNROLL; ++u) {
            const int k = kk + u;
            na = d * (na + 1.f);                     // uniform, 1 op per row
            float pr[VEC];
            #pragma unroll
            for (int j = 0; j < VEC; ++j) {
                const bool  xb = (mask[j] >> k) & 1ull;
                const float mo = m[j];               // = na1_t (exact identity)
                m[j]   = d * (mo + (xb ? 1.f : 0.f));
                n11[j] = d * (n11[j] + ((xb && pb[j]) ? 1.f : 0.f));
                const float num = xb ? (n11[j] + 1.f) : (m[j] - n11[j] + 1.f);
                const float den = xb ? (mo + 2.f)     : (na - mo + 2.f);
                pr[j] = num * __builtin_amdgcn_rcpf(den);   // ONE rcp per element
                pb[j] = xb;
            }
            v4f ov;
            #pragma unroll
            for (int j = 0; j < VEC; ++j) ov[j] = pr[j];
            __builtin_nontemporal_store(ov, reinterpret_cast<v4f*>(q + (size_t)u * B_DIM));
        }
        q += (size_t)UNROLL * B_DIM;
    }
}

extern "C" void kernel_launch(void* const* d_in, const int* in_sizes, int n_in,
                              void* d_out, int out_size, void* d_ws, size_t ws_size,
                              hipStream_t stream) {
    const float* x  = (const float*)d_in[0];
    const float* dr = (const float*)d_in[1];
    float* ws  = (float*)d_ws;    // needs 8 MiB
    float* out = (float*)d_out;

    dim3 blk(256);
    dim3 grid1(B_DIM / VEC / 256, NCHUNK);   // (8, 64) = 512 blocks
    partial_kernel<<<grid1, blk, 0, stream>>>(x, dr, ws);
    scan_kernel<<<(2 * B_DIM) / 256, blk, 0, stream>>>(dr, ws);
    final_kernel<<<grid1, blk, 0, stream>>>(dr, ws, out);
}